// Round 7
// baseline (354.009 us; speedup 1.0000x reference)
//
#include <hip/hip_runtime.h>
#include <cstdint>
#include <cstddef>

#define NB 4
#define NP 4096
#define OD 128
#define LOG2E 1.44269504f

typedef _Float16 h16;
typedef _Float16 h16x8 __attribute__((ext_vector_type(8)));
typedef _Float16 h16x4 __attribute__((ext_vector_type(4)));
typedef _Float16 h16x2 __attribute__((ext_vector_type(2)));
typedef float    f32x4 __attribute__((ext_vector_type(4)));

// Barrier that waits LDS ops only — global loads stay in flight (no vmcnt drain).
__device__ __forceinline__ void lgkm_barrier() {
    asm volatile("s_waitcnt lgkmcnt(0)\n\ts_barrier" ::: "memory");
}

__device__ __forceinline__ h16x8 pack8(f32x4 a, f32x4 b) {
    h16x2 p0 = __builtin_bit_cast(h16x2, __builtin_amdgcn_cvt_pkrtz(a[0], a[1]));
    h16x2 p1 = __builtin_bit_cast(h16x2, __builtin_amdgcn_cvt_pkrtz(a[2], a[3]));
    h16x2 p2 = __builtin_bit_cast(h16x2, __builtin_amdgcn_cvt_pkrtz(b[0], b[1]));
    h16x2 p3 = __builtin_bit_cast(h16x2, __builtin_amdgcn_cvt_pkrtz(b[2], b[3]));
    return (h16x8){p0[0], p0[1], p1[0], p1[1], p2[0], p2[1], p3[0], p3[1]};
}

// ---------------------------------------------------------------------------
// W fp32 -> fp16, fragment-major: slot g = ((mat*32 + kc)*8 + ogrp)*64 + lane,
// value[j] = W[mat][o = 16*ogrp + (lane&15)][k = 32*kc + 8*(lane>>4) + j].
// A wave's A-fragment for (mat,kc,ogrp) is one contiguous 1 KB dwordx4 load.
// ---------------------------------------------------------------------------
__global__ __launch_bounds__(256) void wcvt(
    const float* __restrict__ Wq, const float* __restrict__ Wk,
    const float* __restrict__ Wv, h16* __restrict__ W16f)
{
    int g = blockIdx.x * 256 + threadIdx.x;   // 49152 slots
    int mat = g >> 14, r = g & 16383;
    int kc = r >> 9, ogrp = (r >> 6) & 7, l = r & 63;
    int q2 = l >> 4, lr = l & 15;
    const float* W = (mat == 0) ? Wq : (mat == 1) ? Wk : Wv;
    const float* src = W + (size_t)(16 * ogrp + lr) * 1024 + 32 * kc + 8 * q2;
    f32x4 a = *(const f32x4*)src;
    f32x4 b = *(const f32x4*)(src + 4);
    h16x8 h = {(h16)a.x, (h16)a.y, (h16)a.z, (h16)a.w,
               (h16)b.x, (h16)b.y, (h16)b.z, (h16)b.w};
    *(h16x8*)&W16f[(size_t)g * 8] = h;
}

// ---------------------------------------------------------------------------
// Fused Q/K/V conv-GEMM, 128o x 32n, grid (128, NB). W fragments loaded
// DIRECTLY global->reg (2-deep pipeline, no LDS, no barrier coupling).
// x via reg->ds_write (2-deep), lgkm-only raw barrier per K-chunk.
// Outputs: qt [b][n][o] natural; ktf/vtf fragment-major for flash.
// ---------------------------------------------------------------------------
__global__ __launch_bounds__(256, 3) void conv_qkv(
    const float* __restrict__ x, const h16* __restrict__ W16f,
    const float* __restrict__ bq, const float* __restrict__ bk,
    const float* __restrict__ bv,
    h16* __restrict__ qt, h16* __restrict__ ktf, h16* __restrict__ vtf)
{
    const int nt = blockIdx.x, b = blockIdx.y;
    const int tid = threadIdx.x, lane = tid & 63, wv = tid >> 6;
    const int lr = lane & 15, qd = lane >> 4;
    const int o_w = 32 * wv;

    __shared__ __align__(16) char smem[11776];
    h16* xbuf = (h16*)smem;                    // 2 buffers x 1024 halfs (2 KB)
    float* biasl = (float*)(smem + 10240);     // 384 floats
    if (tid < 128) {
        biasl[tid] = bq[tid]; biasl[128 + tid] = bk[tid]; biasl[256 + tid] = bv[tid];
    }

    // x: thread (xn 0..31, xc 0..1, xkh 0..3) loads f32x4 (4 kw)
    const int xn = tid >> 3, xc = (tid >> 2) & 1, xkh = tid & 3;
    const float* xbase = x + ((size_t)(b * 64) * 256 + 4 * (nt >> 1) + xkh) * 256
                           + 4 * ((nt & 1) * 32 + xn);
    f32x4 xr[2];
    auto xload = [&](int kc, int sl) {
        xr[sl] = *(const f32x4*)(xbase + (size_t)(2 * kc + xc) * 65536);
    };
    // frag-major dest: (tn = xn>>4, qd' = 2*xc + (xkh>>1), lr' = xn&15, j0 = (xkh&1)*4)
    const int xdst = ((xn >> 4) * 64 + (2 * xc + (xkh >> 1)) * 16 + (xn & 15)) * 8 + (xkh & 1) * 4;
    auto xwrite = [&](int sl, int bs) {
        h16x4 h = {(h16)xr[sl].x, (h16)xr[sl].y, (h16)xr[sl].z, (h16)xr[sl].w};
        *(h16x4*)&xbuf[bs * 1024 + xdst] = h;
    };

    h16x8 wreg[2][3][2];
    auto wload = [&](int kc, int bs) {
#pragma unroll
        for (int mat = 0; mat < 3; ++mat)
#pragma unroll
            for (int to = 0; to < 2; ++to)
                wreg[bs][mat][to] = *(const h16x8*)&W16f[
                    ((((size_t)mat * 32 + kc) * 8 + 2 * wv + to) * 64 + lane) * 8];
    };

    f32x4 acc[3][2][2];
#pragma unroll
    for (int m = 0; m < 3; ++m)
#pragma unroll
        for (int a = 0; a < 2; ++a)
#pragma unroll
            for (int c = 0; c < 2; ++c) acc[m][a][c] = (f32x4){0.f, 0.f, 0.f, 0.f};

    xload(0, 0); xload(1, 1);
    wload(0, 0); wload(1, 1);
    xwrite(0, 0);
    lgkm_barrier();

    for (int kc = 0; kc < 32; ++kc) {
        int c = kc & 1;
        if (kc + 1 < 32) xwrite(1 - c, 1 - c);    // stage tile kc+1 (loaded kc-1)

        h16x8 bf[2];
        bf[0] = *(const h16x8*)&xbuf[c * 1024 + lane * 8];
        bf[1] = *(const h16x8*)&xbuf[c * 1024 + (64 + lane) * 8];
#pragma unroll
        for (int mat = 0; mat < 3; ++mat)
#pragma unroll
            for (int to = 0; to < 2; ++to)
#pragma unroll
                for (int tn = 0; tn < 2; ++tn)
                    acc[mat][to][tn] = __builtin_amdgcn_mfma_f32_16x16x32_f16(
                        wreg[c][mat][to], bf[tn], acc[mat][to][tn], 0, 0, 0);

        if (kc + 2 < 32) { xload(kc + 2, c); wload(kc + 2, c); }
        lgkm_barrier();
    }

    __syncthreads();
    const int n0 = nt * 32;
    h16* bnc = (h16*)smem;
    // Q (scaled by log2e) natural [b][n][o]; K fragment-major with softmax row-perm
#pragma unroll
    for (int mat = 0; mat < 2; ++mat) {
        const float qs = (mat == 0) ? LOG2E : 1.0f;
#pragma unroll
        for (int to = 0; to < 2; ++to)
#pragma unroll
            for (int tn = 0; tn < 2; ++tn) {
                int ob = o_w + 16 * to + 4 * qd;
                int n  = 16 * tn + lr;
                h16x4 hv = {(h16)((acc[mat][to][tn][0] + biasl[mat * 128 + ob]) * qs),
                            (h16)((acc[mat][to][tn][1] + biasl[mat * 128 + ob + 1]) * qs),
                            (h16)((acc[mat][to][tn][2] + biasl[mat * 128 + ob + 2]) * qs),
                            (h16)((acc[mat][to][tn][3] + biasl[mat * 128 + ob + 3]) * qs)};
                *(h16x4*)&bnc[n * 136 + ob] = hv;
            }
        __syncthreads();
        if (mat == 0) {
#pragma unroll
            for (int j = 0; j < 2; ++j) {
                int s = tid + 256 * j;
                int n = s >> 4, oc = s & 15;
                *(h16x8*)(qt + ((size_t)(b * NP + n0 + n)) * OD + 8 * oc) =
                    *(h16x8*)&bnc[n * 136 + 8 * oc];
            }
        } else {
#pragma unroll
            for (int j = 0; j < 2; ++j) {
                int s = tid + 256 * j;
                int mt = s >> 8, kc2 = (s >> 6) & 3, l = s & 63;
                int q2 = l >> 4, r2 = l & 15;
                int mlcl = 8 * ((r2 >> 2) & 3) + 4 * mt + (r2 & 3);
                *(h16x8*)&ktf[((((size_t)b * 256 + 2 * nt + mt) * 4 + kc2) * 64 + l) * 8] =
                    *(h16x8*)&bnc[mlcl * 136 + 32 * kc2 + 8 * q2];
            }
        }
        __syncthreads();
    }
    // V fragment-major: vtf chunk ((b*8+to)*128 + nt), value = V[16to+lr][8qd+j]
    {
#pragma unroll
        for (int to = 0; to < 2; ++to)
#pragma unroll
            for (int tn = 0; tn < 2; ++tn)
#pragma unroll
                for (int r = 0; r < 4; ++r) {
                    int o = o_w + 16 * to + 4 * qd + r;
                    int n = 16 * tn + lr;
                    bnc[o * 40 + n] = (h16)(acc[2][to][tn][r] + biasl[256 + o]);
                }
        __syncthreads();
#pragma unroll
        for (int j = 0; j < 2; ++j) {
            int s = tid + 256 * j;
            int to = s >> 6, l = s & 63;
            int q2 = l >> 4, r2 = l & 15;
            *(h16x8*)&vtf[((((size_t)b * 8 + to) * 128 + nt) * 64 + l) * 8] =
                *(h16x8*)&bnc[(16 * to + r2) * 40 + 8 * q2];
        }
    }
}

// ---------------------------------------------------------------------------
// Flash attention, SP=8 split-K. Grid (32 g=(sp,b), 32 nt) -> XCD = g%8 pins
// each XCD to one b + 4 sp-ranges (~1 MB K/V, L2-resident). 4 waves x 32 Q.
// K/V: plain global->reg (fragment-major, contiguous 1KB loads) -> ds_write,
// double-buffered; lgkm-only raw barrier (global loads never drained).
// S^T = mfma(K,Q); K rows pre-permuted so P exits in B-operand layout; PV at
// K=32 from registers. exp2-domain online softmax.
// ---------------------------------------------------------------------------
__global__ __launch_bounds__(256, 3) void flash_attn(
    const h16* __restrict__ qt, const h16* __restrict__ ktf,
    const h16* __restrict__ vtf, h16* __restrict__ po, float2* __restrict__ ml)
{
    constexpr int NIT = 16;                       // 512 m per split, 32 per iter
    const int g = blockIdx.x, nt = blockIdx.y;
    const int sp = g >> 2, b = g & 3;
    const int tid = threadIdx.x, lane = tid & 63, wv = tid >> 6;
    const int lr = lane & 15, qd = lane >> 4;

    __shared__ __align__(16) h16 smem[2][8192];   // 16 chunks x 512 halfs each

    h16x8 qf[2][4];
#pragma unroll
    for (int rt = 0; rt < 2; ++rt)
#pragma unroll
        for (int kc = 0; kc < 4; ++kc)
            qf[rt][kc] = *(const h16x8*)&qt[((size_t)(b * NP + nt * 128 + 32 * wv + 16 * rt + lr)) * OD
                                            + 32 * kc + 8 * qd];

    float m_run[2] = {-1e30f, -1e30f}, l_run[2] = {0.f, 0.f};
    f32x4 oacc[2][8];
#pragma unroll
    for (int rt = 0; rt < 2; ++rt)
#pragma unroll
        for (int t = 0; t < 8; ++t) oacc[rt][t] = (f32x4){0.f, 0.f, 0.f, 0.f};

    // wave wv stages chunks 4wv..4wv+3 (0..7 = K, 8..15 = V)
    const h16* kptr = ktf + ((size_t)b * 1024 + sp * 128) * 512 + lane * 8;
    const h16* vptr = vtf + ((size_t)b * 1024 + sp * 16) * 512 + lane * 8;
    h16x8 kv[4];
    auto kvload = [&](int it) {
#pragma unroll
        for (int q = 0; q < 4; ++q) {
            int ch = 4 * wv + q;
            kv[q] = (ch < 8)
                ? *(const h16x8*)(kptr + ((size_t)it * 8 + ch) * 512)
                : *(const h16x8*)(vptr + ((size_t)(ch - 8) * 128 + it) * 512);
        }
    };
    auto kvwrite = [&](int bs) {
#pragma unroll
        for (int q = 0; q < 4; ++q)
            *(h16x8*)&smem[bs][(4 * wv + q) * 512 + lane * 8] = kv[q];
    };

    kvload(0); kvwrite(0); kvload(1);
    lgkm_barrier();

    for (int it = 0; it < NIT; ++it) {
        int c = it & 1;
        if (it + 1 < NIT) kvwrite(1 - c);         // stage tile it+1 (loaded it-1)
        if (it + 2 < NIT) kvload(it + 2);         // issue loads, in flight ~1 iter

        // S^T: per lane col n = lr; regs (mt,r) hold m = 8qd + 4mt + r
        f32x4 sc[2][2];
#pragma unroll
        for (int rt = 0; rt < 2; ++rt)
#pragma unroll
            for (int mt = 0; mt < 2; ++mt) sc[rt][mt] = (f32x4){0.f, 0.f, 0.f, 0.f};
#pragma unroll
        for (int mt = 0; mt < 2; ++mt)
#pragma unroll
            for (int kc = 0; kc < 4; ++kc) {
                h16x8 kf = *(const h16x8*)&smem[c][(mt * 4 + kc) * 512 + lane * 8];
                sc[0][mt] = __builtin_amdgcn_mfma_f32_16x16x32_f16(kf, qf[0][kc], sc[0][mt], 0, 0, 0);
                sc[1][mt] = __builtin_amdgcn_mfma_f32_16x16x32_f16(kf, qf[1][kc], sc[1][mt], 0, 0, 0);
            }

        // online softmax, exp2 domain
        h16x8 pf[2];
        float al[2];
#pragma unroll
        for (int rt = 0; rt < 2; ++rt) {
            float mx = fmaxf(fmaxf(fmaxf(sc[rt][0][0], sc[rt][0][1]), fmaxf(sc[rt][0][2], sc[rt][0][3])),
                             fmaxf(fmaxf(sc[rt][1][0], sc[rt][1][1]), fmaxf(sc[rt][1][2], sc[rt][1][3])));
            mx = fmaxf(mx, __shfl_xor(mx, 16));
            mx = fmaxf(mx, __shfl_xor(mx, 32));
            float mn = fmaxf(m_run[rt], mx);
            al[rt] = __builtin_amdgcn_exp2f(m_run[rt] - mn);
            m_run[rt] = mn;
            float rs = 0.f;
#pragma unroll
            for (int mt = 0; mt < 2; ++mt)
#pragma unroll
                for (int r = 0; r < 4; ++r) {
                    float e = __builtin_amdgcn_exp2f(sc[rt][mt][r] - mn);
                    sc[rt][mt][r] = e;
                    rs += e;
                }
            rs += __shfl_xor(rs, 16);
            rs += __shfl_xor(rs, 32);
            l_run[rt] = l_run[rt] * al[rt] + rs;
            pf[rt] = pack8(sc[rt][0], sc[rt][1]);
        }
#pragma unroll
        for (int rt = 0; rt < 2; ++rt)
#pragma unroll
            for (int to = 0; to < 8; ++to)
#pragma unroll
                for (int r = 0; r < 4; ++r) oacc[rt][to][r] *= al[rt];

        // PV at K=32: A = V fragment (natural), B = P (registers)
#pragma unroll
        for (int to = 0; to < 8; ++to) {
            h16x8 va = *(const h16x8*)&smem[c][(8 + to) * 512 + lane * 8];
            oacc[0][to] = __builtin_amdgcn_mfma_f32_16x16x32_f16(va, pf[0], oacc[0][to], 0, 0, 0);
            oacc[1][to] = __builtin_amdgcn_mfma_f32_16x16x32_f16(va, pf[1], oacc[1][to], 0, 0, 0);
        }
        lgkm_barrier();
    }

    // epilogue: normalized fp16 partials + (m,l) in exp2 domain
    const size_t nbase = (size_t)(sp * NB + b) * NP + nt * 128 + 32 * wv;
    if (qd == 0) {
#pragma unroll
        for (int rt = 0; rt < 2; ++rt)
            ml[nbase + 16 * rt + lr] = make_float2(m_run[rt], l_run[rt]);
    }
    float inv[2] = {1.f / l_run[0], 1.f / l_run[1]};
#pragma unroll
    for (int rt = 0; rt < 2; ++rt)
#pragma unroll
        for (int to = 0; to < 8; ++to) {
            h16x4 hv = {(h16)(oacc[rt][to][0] * inv[rt]), (h16)(oacc[rt][to][1] * inv[rt]),
                        (h16)(oacc[rt][to][2] * inv[rt]), (h16)(oacc[rt][to][3] * inv[rt])};
            *(h16x4*)&po[(nbase + 16 * rt + lr) * OD + 16 * to + 4 * qd] = hv;
        }
}

// ---------------------------------------------------------------------------
// Combine SP split partials -> out[b][o][n] fp32.
// ---------------------------------------------------------------------------
template <int SP>
__global__ __launch_bounds__(256) void combine(
    const h16* __restrict__ po, const float2* __restrict__ ml,
    float* __restrict__ out)
{
    const int nt = blockIdx.x, b = blockIdx.y;
    const int n0 = nt * 32, tid = threadIdx.x;
    __shared__ float w[SP][32];
    __shared__ float bn[32 * 137];

    if (tid < 32) {
        int n = n0 + tid;
        float m[SP], l[SP], M = -1e30f;
#pragma unroll
        for (int s = 0; s < SP; ++s) {
            float2 v = ml[(size_t)(s * NB + b) * NP + n];
            m[s] = v.x; l[s] = v.y;
            M = fmaxf(M, m[s]);
        }
        float d = 0.f, e[SP];
#pragma unroll
        for (int s = 0; s < SP; ++s) { e[s] = l[s] * __builtin_amdgcn_exp2f(m[s] - M); d += e[s]; }
        float id = 1.f / d;
#pragma unroll
        for (int s = 0; s < SP; ++s) w[s][tid] = e[s] * id;
    }
    __syncthreads();

#pragma unroll
    for (int j = 0; j < 2; ++j) {
        int s = tid + 256 * j;
        int n = s >> 4, oc = s & 15;
        float acc[8];
#pragma unroll
        for (int k = 0; k < 8; ++k) acc[k] = 0.f;
#pragma unroll
        for (int sp = 0; sp < SP; ++sp) {
            h16x8 v = *(const h16x8*)&po[((size_t)(sp * NB + b) * NP + n0 + n) * OD + 8 * oc];
            float ww = w[sp][n];
#pragma unroll
            for (int k = 0; k < 8; ++k) acc[k] += ww * (float)v[k];
        }
#pragma unroll
        for (int k = 0; k < 8; ++k) bn[n * 137 + 8 * oc + k] = acc[k];
    }
    __syncthreads();

#pragma unroll
    for (int j = 0; j < 4; ++j) {
        int s = tid + 256 * j;
        int o = s >> 3, ng = s & 7;
        f32x4 r = {bn[(4 * ng + 0) * 137 + o], bn[(4 * ng + 1) * 137 + o],
                   bn[(4 * ng + 2) * 137 + o], bn[(4 * ng + 3) * 137 + o]};
        *(f32x4*)&out[((size_t)(b * OD + o)) * NP + n0 + 4 * ng] = r;
    }
}

extern "C" void kernel_launch(void* const* d_in, const int* in_sizes, int n_in,
                              void* d_out, int out_size, void* d_ws, size_t ws_size,
                              hipStream_t stream) {
    const float* x  = (const float*)d_in[0];
    const float* Wq = (const float*)d_in[1];
    const float* bq = (const float*)d_in[2];
    const float* Wk = (const float*)d_in[3];
    const float* bk = (const float*)d_in[4];
    const float* Wv = (const float*)d_in[5];
    const float* bv = (const float*)d_in[6];

    h16* qtp  = (h16*)d_ws;                                  // 4 MB
    h16* ktf  = qtp + (size_t)NB * NP * OD;                  // 4 MB (frag-major)
    h16* vtf  = ktf + (size_t)NB * NP * OD;                  // 4 MB (frag-major)
    h16* W16f = vtf + (size_t)NB * NP * OD;                  // 768 KB (frag-major)
    h16* po   = W16f + (size_t)3 * 32 * 512 * 8;             // 32 MB (SP=8)
    float2* ml = (float2*)(po + (size_t)8 * NB * NP * OD);   // 1 MB
    float* out = (float*)d_out;

    wcvt<<<dim3(192), 256, 0, stream>>>(Wq, Wk, Wv, W16f);
    conv_qkv<<<dim3(128, NB), 256, 0, stream>>>(x, W16f, bq, bk, bv, qtp, ktf, vtf);
    flash_attn<<<dim3(32, 32), 256, 0, stream>>>(qtp, ktf, vtf, po, ml);
    combine<8><<<dim3(128, NB), 256, 0, stream>>>(po, ml, out);
}